// Round 1
// baseline (1510.996 us; speedup 1.0000x reference)
//
#include <hip/hip_runtime.h>
#include <hip/hip_bf16.h>
#include <math.h>

#define Bn 64
#define Sn 512
#define Hn 1024
#define Tn 48
#define CH 64
#define NTH 192

#define LOG2E 1.4426950408889634f
#define LN2f  0.6931471805599453f

#define PRED_OFF (Bn*Sn*Tn)
#define LOSS_OFF (PRED_OFF + Bn*Sn)

// ======================= GEMM: feat = x @ W + b =======================
#define BM 64
#define BK 64

#define DOT4(ACC,A,B) { ACC += (A).x*(B).x; ACC += (A).y*(B).y; ACC += (A).z*(B).z; ACC += (A).w*(B).w; }

__global__ __launch_bounds__(256) void gemm_feat(
    const float* __restrict__ x, const float* __restrict__ W,
    const float* __restrict__ bias, float* __restrict__ feat)
{
  __shared__ __align__(16) float xs[BM][BK+4];   // stride 68 -> no bank conflicts
  __shared__ __align__(16) float wsT[Tn][BK+4];
  const int tid = threadIdx.x;
  const int tx = tid & 15;   // col group: cols tx*3..tx*3+2
  const int ty = tid >> 4;   // row group: rows ty*4..ty*4+3
  const size_t row0 = (size_t)blockIdx.x * BM;

  float acc[4][3];
  #pragma unroll
  for (int r = 0; r < 4; ++r)
    #pragma unroll
    for (int c = 0; c < 3; ++c) acc[r][c] = 0.f;

  for (int k0 = 0; k0 < Hn; k0 += BK) {
    // stage x tile: 64 rows x 64 k
    #pragma unroll
    for (int p = 0; p < 4; ++p) {
      const int rr = ty + p*16;
      const float4 v = *reinterpret_cast<const float4*>(&x[(row0+rr)*Hn + k0 + tx*4]);
      *reinterpret_cast<float4*>(&xs[rr][tx*4]) = v;
    }
    // stage W^T tile: wsT[t][kk] = W[k0+kk][t]
    #pragma unroll
    for (int i = 0; i < 12; ++i) {
      const int id = tid + i*256;
      const int kk = id / Tn;
      const int t  = id - kk*Tn;
      wsT[t][kk] = W[(size_t)(k0+kk)*Tn + t];
    }
    __syncthreads();
    #pragma unroll 4
    for (int kk = 0; kk < BK; kk += 4) {
      const float4 a0 = *reinterpret_cast<const float4*>(&xs[ty*4+0][kk]);
      const float4 a1 = *reinterpret_cast<const float4*>(&xs[ty*4+1][kk]);
      const float4 a2 = *reinterpret_cast<const float4*>(&xs[ty*4+2][kk]);
      const float4 a3 = *reinterpret_cast<const float4*>(&xs[ty*4+3][kk]);
      const float4 w0 = *reinterpret_cast<const float4*>(&wsT[tx*3+0][kk]);
      const float4 w1 = *reinterpret_cast<const float4*>(&wsT[tx*3+1][kk]);
      const float4 w2 = *reinterpret_cast<const float4*>(&wsT[tx*3+2][kk]);
      DOT4(acc[0][0], a0, w0) DOT4(acc[0][1], a0, w1) DOT4(acc[0][2], a0, w2)
      DOT4(acc[1][0], a1, w0) DOT4(acc[1][1], a1, w1) DOT4(acc[1][2], a1, w2)
      DOT4(acc[2][0], a2, w0) DOT4(acc[2][1], a2, w1) DOT4(acc[2][2], a2, w2)
      DOT4(acc[3][0], a3, w0) DOT4(acc[3][1], a3, w1) DOT4(acc[3][2], a3, w2)
    }
    __syncthreads();
  }
  #pragma unroll
  for (int c = 0; c < 3; ++c) {
    const int col = tx*3 + c;
    const float bv = bias[col];
    #pragma unroll
    for (int r = 0; r < 4; ++r) {
      feat[(row0 + ty*4 + r)*Tn + col] = acc[r][c] + bv;
    }
  }
}

// ======================= CRF scans (1 block per batch) =======================
// wave0: log-partition forward; wave1: Viterbi forward + backtrace; wave2: gold.
// All scores pre-scaled by log2(e): exp->exp2, log->log2; argmax invariant.

__global__ __launch_bounds__(NTH) void crf_kernel(
    const float* __restrict__ feat,
    const int* __restrict__ mask,
    const int* __restrict__ labels,
    const float* __restrict__ trans,
    const float* __restrict__ startv,
    const float* __restrict__ endv,
    float* __restrict__ pred_out,
    float* __restrict__ loss_part)
{
  __shared__ __align__(16) float em[CH][Tn];      // 12 KB (log2-scaled emissions, one chunk)
  __shared__ float tr2[Tn*Tn];                    // 9 KB (log2-scaled transitions)
  __shared__ unsigned char bp[Sn][Tn];            // 24 KB backpointers
  __shared__ unsigned char lab[Sn];
  __shared__ unsigned char msk[Sn];
  __shared__ unsigned char pred[Sn];
  __shared__ __align__(16) float alds[Tn];        // partition state
  __shared__ __align__(16) float vlds[Tn];        // viterbi state
  __shared__ float red[2];                        // [0]=gold2 [1]=logZ2

  const int b    = blockIdx.x;
  const int tid  = threadIdx.x;
  const int wave = tid >> 6;
  const int lane = tid & 63;
  const float* fb = feat + (size_t)b * Sn * Tn;

  for (int i = tid; i < Tn*Tn; i += NTH) tr2[i] = trans[i] * LOG2E;
  for (int i = tid; i < Sn; i += NTH) {
    lab[i] = (unsigned char)labels[b*Sn + i];
    msk[i] = (unsigned char)(mask[b*Sn + i] != 0);
  }
  __syncthreads();

  // per-lane column of transitions (scaled): trT[i] = log2e * trans[i][lane]
  float trT[Tn];
  if (wave < 2 && lane < Tn) {
    #pragma unroll
    for (int i = 0; i < Tn; ++i) trT[i] = tr2[i*Tn + lane];
  }

  float alpha = 0.f, vstate = 0.f;
  float gE = 0.f, gT = 0.f;
  int gCnt = 0;

  for (int c = 0; c < Sn/CH; ++c) {
    __syncthreads();   // previous chunk fully consumed
    {
      const float4* src = reinterpret_cast<const float4*>(fb + (size_t)c*CH*Tn);
      float4* dst = reinterpret_cast<float4*>(&em[0][0]);
      for (int i = tid; i < CH*Tn/4; i += NTH) {
        float4 q = src[i];
        q.x *= LOG2E; q.y *= LOG2E; q.z *= LOG2E; q.w *= LOG2E;
        dst[i] = q;
      }
    }
    __syncthreads();

    if (wave == 0) {
      // ---------------- log-partition ----------------
      if (lane < Tn) {
        int s = 0;
        if (c == 0) {
          alpha = startv[lane]*LOG2E + em[0][lane];
          alds[lane] = alpha;
          s = 1;
        }
        for (; s < CH; ++s) {
          const int t = c*CH + s;
          float a[Tn];
          const float4* av = reinterpret_cast<const float4*>(alds);
          #pragma unroll
          for (int k = 0; k < Tn/4; ++k) {
            const float4 q = av[k];
            a[4*k] = q.x; a[4*k+1] = q.y; a[4*k+2] = q.z; a[4*k+3] = q.w;
          }
          float sv[Tn];
          #pragma unroll
          for (int i = 0; i < Tn; ++i) sv[i] = a[i] + trT[i];
          float mA = sv[0], mB = sv[1], mC = sv[2], mD = sv[3];
          float mE = sv[4], mF = sv[5], mG = sv[6], mH = sv[7];
          #pragma unroll
          for (int i = 8; i < Tn; i += 8) {
            mA = fmaxf(mA, sv[i]);   mB = fmaxf(mB, sv[i+1]);
            mC = fmaxf(mC, sv[i+2]); mD = fmaxf(mD, sv[i+3]);
            mE = fmaxf(mE, sv[i+4]); mF = fmaxf(mF, sv[i+5]);
            mG = fmaxf(mG, sv[i+6]); mH = fmaxf(mH, sv[i+7]);
          }
          const float mm = fmaxf(fmaxf(fmaxf(mA,mB), fmaxf(mC,mD)),
                                 fmaxf(fmaxf(mE,mF), fmaxf(mG,mH)));
          float e0=0.f,e1=0.f,e2=0.f,e3=0.f,e4=0.f,e5=0.f,e6=0.f,e7=0.f;
          #pragma unroll
          for (int i = 0; i < Tn; i += 8) {
            e0 += exp2f(sv[i]  -mm); e1 += exp2f(sv[i+1]-mm);
            e2 += exp2f(sv[i+2]-mm); e3 += exp2f(sv[i+3]-mm);
            e4 += exp2f(sv[i+4]-mm); e5 += exp2f(sv[i+5]-mm);
            e6 += exp2f(sv[i+6]-mm); e7 += exp2f(sv[i+7]-mm);
          }
          const float ssum = ((e0+e1)+(e2+e3)) + ((e4+e5)+(e6+e7));
          const float na = mm + log2f(ssum) + em[s][lane];
          alpha = msk[t] ? na : alpha;
          alds[lane] = alpha;
        }
      }
    } else if (wave == 1) {
      // ---------------- Viterbi forward ----------------
      if (lane < Tn) {
        int s = 0;
        if (c == 0) {
          vstate = startv[lane]*LOG2E + em[0][lane];
          vlds[lane] = vstate;
          s = 1;
        }
        for (; s < CH; ++s) {
          const int t = c*CH + s;
          float a[Tn];
          const float4* vv = reinterpret_cast<const float4*>(vlds);
          #pragma unroll
          for (int k = 0; k < Tn/4; ++k) {
            const float4 q = vv[k];
            a[4*k] = q.x; a[4*k+1] = q.y; a[4*k+2] = q.z; a[4*k+3] = q.w;
          }
          float sv[Tn];
          #pragma unroll
          for (int i = 0; i < Tn; ++i) sv[i] = a[i] + trT[i];
          // first-occurrence argmax via ordered tree (strict > keeps lowest index)
          float v0[24]; int j0[24];
          #pragma unroll
          for (int k = 0; k < 24; ++k) {
            const bool g = sv[2*k+1] > sv[2*k];
            v0[k] = g ? sv[2*k+1] : sv[2*k];
            j0[k] = g ? (2*k+1) : (2*k);
          }
          float v1[12]; int j1[12];
          #pragma unroll
          for (int k = 0; k < 12; ++k) {
            const bool g = v0[2*k+1] > v0[2*k];
            v1[k] = g ? v0[2*k+1] : v0[2*k];
            j1[k] = g ? j0[2*k+1] : j0[2*k];
          }
          float v2[6]; int j2[6];
          #pragma unroll
          for (int k = 0; k < 6; ++k) {
            const bool g = v1[2*k+1] > v1[2*k];
            v2[k] = g ? v1[2*k+1] : v1[2*k];
            j2[k] = g ? j1[2*k+1] : j1[2*k];
          }
          float v3[3]; int j3[3];
          #pragma unroll
          for (int k = 0; k < 3; ++k) {
            const bool g = v2[2*k+1] > v2[2*k];
            v3[k] = g ? v2[2*k+1] : v2[2*k];
            j3[k] = g ? j2[2*k+1] : j2[2*k];
          }
          float bb = v3[0]; int bj = j3[0];
          if (v3[1] > bb) { bb = v3[1]; bj = j3[1]; }
          if (v3[2] > bb) { bb = v3[2]; bj = j3[2]; }
          const float best = bb + em[s][lane];
          const int keep = (int)msk[t];
          vstate = keep ? best : vstate;
          const int bpv = keep ? bj : lane;
          bp[t][lane] = (unsigned char)bpv;
          vlds[lane] = vstate;
        }
      }
    } else {
      // ---------------- gold score partials ----------------
      const int sg = c*CH + lane;   // lane 0..63 <-> step within chunk
      const float mk = msk[sg] ? 1.f : 0.f;
      gE += mk * em[lane][lab[sg]];
      if (sg >= 1) gT += mk * tr2[(int)lab[sg-1]*Tn + (int)lab[sg]];
      gCnt += (int)msk[sg];
    }
  }

  // ---------------- finalize ----------------
  if (wave == 0) {
    const float fv = (lane < Tn) ? alpha + endv[lane]*LOG2E : -INFINITY;
    float m = fv;
    #pragma unroll
    for (int off = 32; off; off >>= 1) m = fmaxf(m, __shfl_xor(m, off));
    float e = (lane < Tn) ? exp2f(fv - m) : 0.f;
    #pragma unroll
    for (int off = 32; off; off >>= 1) e += __shfl_xor(e, off);
    if (lane == 0) red[1] = m + log2f(e);          // logZ in log2 units
  } else if (wave == 1) {
    float fv = (lane < Tn) ? vstate + endv[lane]*LOG2E : -INFINITY;
    int   fi = (lane < Tn) ? lane : 1000;
    #pragma unroll
    for (int off = 32; off; off >>= 1) {
      const float ov = __shfl_xor(fv, off);
      const int   oi = __shfl_xor(fi, off);
      if (ov > fv || (ov == fv && oi < fi)) { fv = ov; fi = oi; }
    }
    if (lane == 0) {
      int tag = fi;
      pred[Sn-1] = (unsigned char)tag;
      for (int t = Sn-1; t >= 1; --t) {
        tag = bp[t][tag];
        pred[t-1] = (unsigned char)tag;
      }
    }
  } else {
    float g = gE + gT;
    #pragma unroll
    for (int off = 32; off; off >>= 1) g += __shfl_xor(g, off);
    int cnt = gCnt;
    #pragma unroll
    for (int off = 32; off; off >>= 1) cnt += __shfl_xor(cnt, off);
    if (lane == 0) {
      g += startv[(int)lab[0]]*LOG2E + endv[(int)lab[cnt-1]]*LOG2E;
      red[0] = g;                                   // gold in log2 units
    }
  }
  __syncthreads();

  for (int s = tid; s < Sn; s += NTH)
    pred_out[(size_t)b*Sn + s] = msk[s] ? (float)pred[s] : 0.f;
  if (tid == 0)
    loss_part[b] = (red[1] - red[0]) * LN2f;        // -(gold - logZ), back to ln units
}

__global__ void loss_reduce(const float* __restrict__ lp, float* __restrict__ out)
{
  const int lane = threadIdx.x;
  float v = lp[lane];
  #pragma unroll
  for (int off = 32; off; off >>= 1) v += __shfl_xor(v, off);
  if (lane == 0) out[0] = v;
}

extern "C" void kernel_launch(void* const* d_in, const int* in_sizes, int n_in,
                              void* d_out, int out_size, void* d_ws, size_t ws_size,
                              hipStream_t stream) {
  const float* x      = (const float*)d_in[0];
  const int*   mask   = (const int*)  d_in[1];
  const int*   labels = (const int*)  d_in[2];
  const float* W      = (const float*)d_in[3];
  const float* bias   = (const float*)d_in[4];
  const float* trans  = (const float*)d_in[5];
  const float* startv = (const float*)d_in[6];
  const float* endv   = (const float*)d_in[7];

  float* out  = (float*)d_out;
  float* feat = out;                 // output 0: features [B][S][T]
  float* pred = out + PRED_OFF;      // output 1: pred_labels as float [B][S]
  float* loss = out + LOSS_OFF;      // output 2: scalar loss
  float* lp   = (float*)d_ws;        // 64 per-batch loss partials

  gemm_feat<<<(Bn*Sn)/BM, 256, 0, stream>>>(x, W, bias, feat);
  crf_kernel<<<Bn, NTH, 0, stream>>>(feat, mask, labels, trans, startv, endv, pred, lp);
  loss_reduce<<<1, 64, 0, stream>>>(lp, loss);
}

// Round 2
// 386.011 us; speedup vs baseline: 3.9144x; 3.9144x over previous
//
#include <hip/hip_runtime.h>
#include <hip/hip_bf16.h>
#include <math.h>

#define Bn 64
#define Sn 512
#define Hn 1024
#define Tn 48

#define LOG2E 1.4426950408889634f
#define LN2f  0.6931471805599453f

#define PRED_OFF (Bn*Sn*Tn)
#define LOSS_OFF (PRED_OFF + Bn*Sn)

#define RL(x,i) __int_as_float(__builtin_amdgcn_readlane(__float_as_int(x),(i)))

#if __has_builtin(__builtin_amdgcn_exp2f)
#define EXP2(x) __builtin_amdgcn_exp2f(x)
#else
#define EXP2(x) exp2f(x)
#endif
#if __has_builtin(__builtin_amdgcn_logf)
#define LOG2(x) __builtin_amdgcn_logf(x)
#else
#define LOG2(x) log2f(x)
#endif

// ======================= GEMM: feat = x @ W + b =======================
// BM=128 rows/block, full N=48. 256 threads, per-thread 4 rows x 6 cols.
// Register-prefetch double staging: load chunk k+1 to regs while computing k.
#define DOT4(ACC,A,B) { ACC += (A).x*(B).x; ACC += (A).y*(B).y; ACC += (A).z*(B).z; ACC += (A).w*(B).w; }

__global__ __launch_bounds__(256) void gemm_feat(
    const float* __restrict__ x, const float* __restrict__ W,
    const float* __restrict__ bias, float* __restrict__ feat)
{
  __shared__ __align__(16) float xs[128][68];
  __shared__ __align__(16) float wsT[Tn][68];
  const int tid = threadIdx.x;
  const int tx = tid & 7;        // col group: cols tx*6 .. tx*6+5
  const int ty = tid >> 3;       // row group: rows ty*4 .. ty*4+3
  const size_t row0 = (size_t)blockIdx.x * 128;
  const int srr = tid >> 4;        // 0..15
  const int scc = (tid & 15) * 4;  // 0..60

  float4 xreg[8];
  float  wreg[12];
  #pragma unroll
  for (int p = 0; p < 8; ++p)
    xreg[p] = *reinterpret_cast<const float4*>(&x[(row0 + srr + p*16)*Hn + scc]);
  #pragma unroll
  for (int i = 0; i < 12; ++i) {
    const int id = tid + i*256; const int kk = id/Tn; const int t = id - kk*Tn;
    wreg[i] = W[(size_t)kk*Tn + t];
  }

  float acc[4][6];
  #pragma unroll
  for (int r = 0; r < 4; ++r)
    #pragma unroll
    for (int c = 0; c < 6; ++c) acc[r][c] = 0.f;

  for (int k0 = 0; k0 < Hn; k0 += 64) {
    #pragma unroll
    for (int p = 0; p < 8; ++p)
      *reinterpret_cast<float4*>(&xs[srr + p*16][scc]) = xreg[p];
    #pragma unroll
    for (int i = 0; i < 12; ++i) {
      const int id = tid + i*256; const int kk = id/Tn; const int t = id - kk*Tn;
      wsT[t][kk] = wreg[i];
    }
    __syncthreads();
    if (k0 + 64 < Hn) {
      #pragma unroll
      for (int p = 0; p < 8; ++p)
        xreg[p] = *reinterpret_cast<const float4*>(&x[(row0 + srr + p*16)*Hn + (k0+64) + scc]);
      #pragma unroll
      for (int i = 0; i < 12; ++i) {
        const int id = tid + i*256; const int kk = id/Tn; const int t = id - kk*Tn;
        wreg[i] = W[(size_t)(k0 + 64 + kk)*Tn + t];
      }
    }
    #pragma unroll 4
    for (int kk = 0; kk < 64; kk += 4) {
      const float4 a0 = *reinterpret_cast<const float4*>(&xs[ty*4+0][kk]);
      const float4 a1 = *reinterpret_cast<const float4*>(&xs[ty*4+1][kk]);
      const float4 a2 = *reinterpret_cast<const float4*>(&xs[ty*4+2][kk]);
      const float4 a3 = *reinterpret_cast<const float4*>(&xs[ty*4+3][kk]);
      const float4 w0 = *reinterpret_cast<const float4*>(&wsT[tx*6+0][kk]);
      const float4 w1 = *reinterpret_cast<const float4*>(&wsT[tx*6+1][kk]);
      const float4 w2 = *reinterpret_cast<const float4*>(&wsT[tx*6+2][kk]);
      const float4 w3 = *reinterpret_cast<const float4*>(&wsT[tx*6+3][kk]);
      const float4 w4 = *reinterpret_cast<const float4*>(&wsT[tx*6+4][kk]);
      const float4 w5 = *reinterpret_cast<const float4*>(&wsT[tx*6+5][kk]);
      DOT4(acc[0][0],a0,w0) DOT4(acc[0][1],a0,w1) DOT4(acc[0][2],a0,w2)
      DOT4(acc[0][3],a0,w3) DOT4(acc[0][4],a0,w4) DOT4(acc[0][5],a0,w5)
      DOT4(acc[1][0],a1,w0) DOT4(acc[1][1],a1,w1) DOT4(acc[1][2],a1,w2)
      DOT4(acc[1][3],a1,w3) DOT4(acc[1][4],a1,w4) DOT4(acc[1][5],a1,w5)
      DOT4(acc[2][0],a2,w0) DOT4(acc[2][1],a2,w1) DOT4(acc[2][2],a2,w2)
      DOT4(acc[2][3],a2,w3) DOT4(acc[2][4],a2,w4) DOT4(acc[2][5],a2,w5)
      DOT4(acc[3][0],a3,w0) DOT4(acc[3][1],a3,w1) DOT4(acc[3][2],a3,w2)
      DOT4(acc[3][3],a3,w3) DOT4(acc[3][4],a3,w4) DOT4(acc[3][5],a3,w5)
    }
    __syncthreads();
  }
  #pragma unroll
  for (int c = 0; c < 6; ++c) {
    const int col = tx*6 + c;
    const float bv = bias[col];
    #pragma unroll
    for (int r = 0; r < 4; ++r)
      feat[(row0 + ty*4 + r)*Tn + col] = acc[r][c] + bv;
  }
}

// ======================= CRF: 192 single-wave blocks =======================
// role 0 (blocks 0..63):   log-partition forward (log2 domain, re-based defer-max)
// role 1 (blocks 64..127): Viterbi forward (raw ln domain, bit-exact) + backtrace
// role 2 (blocks 128..191): gold score
__global__ __launch_bounds__(64, 1) void crf_kernel(
    const float* __restrict__ feat,
    const int* __restrict__ mask,
    const int* __restrict__ labels,
    const float* __restrict__ trans,
    const float* __restrict__ startv,
    const float* __restrict__ endv,
    float* __restrict__ pred_out,
    float* __restrict__ wsLogZ,
    float* __restrict__ wsGold)
{
  __shared__ unsigned char bpL[Sn*64];   // backpointers, row stride 64
  __shared__ unsigned char predL[Sn];

  const int role = blockIdx.x >> 6;
  const int b    = blockIdx.x & 63;
  const int lane = threadIdx.x;
  const float* fb = feat + (size_t)b * Sn * Tn;

  // sequence length (mask is a prefix mask)
  int lc = 0;
  #pragma unroll
  for (int it = 0; it < Sn/64; ++it) lc += (mask[(size_t)b*Sn + it*64 + lane] != 0);
  #pragma unroll
  for (int off = 32; off; off >>= 1) lc += __shfl_xor(lc, off);
  const int len = lc;

  const int j = (lane < Tn) ? lane : (Tn - 1);

  if (role == 0) {
    // ---------------- log-partition (log2 domain) ----------------
    float4 trT[12];
    #pragma unroll
    for (int k = 0; k < 12; ++k) {
      trT[k].x = trans[(4*k+0)*Tn + j] * LOG2E;
      trT[k].y = trans[(4*k+1)*Tn + j] * LOG2E;
      trT[k].z = trans[(4*k+2)*Tn + j] * LOG2E;
      trT[k].w = trans[(4*k+3)*Tn + j] * LOG2E;
    }
    const float a0 = (startv[j] + fb[j]) * LOG2E;
    float Zref = RL(a0, 0);
    float beta = a0 - Zref;          // beta[0] == 0 always; spread bounded (~10)
    float em_cur = fb[Tn + j];
    for (int t = 1; t < len; ++t) {
      const int tn = (t + 1 < len) ? (t + 1) : t;
      const float em_nxt = fb[(size_t)tn*Tn + j];
      float s0 = 0.f, s1 = 0.f, s2 = 0.f, s3 = 0.f;
      #pragma unroll
      for (int k = 0; k < 12; ++k) {
        s0 += EXP2(RL(beta, 4*k+0) + trT[k].x);
        s1 += EXP2(RL(beta, 4*k+1) + trT[k].y);
        s2 += EXP2(RL(beta, 4*k+2) + trT[k].z);
        s3 += EXP2(RL(beta, 4*k+3) + trT[k].w);
      }
      const float dj = LOG2((s0 + s1) + (s2 + s3)) + em_cur * LOG2E;
      const float d0 = RL(dj, 0);
      Zref += d0;
      beta = dj - d0;
      em_cur = em_nxt;
    }
    float fv = (lane < Tn) ? beta + endv[lane] * LOG2E : -INFINITY;
    float m = fv;
    #pragma unroll
    for (int off = 32; off; off >>= 1) m = fmaxf(m, __shfl_xor(m, off));
    float e = (lane < Tn) ? EXP2(fv - m) : 0.f;
    #pragma unroll
    for (int off = 32; off; off >>= 1) e += __shfl_xor(e, off);
    if (lane == 0) wsLogZ[b] = (Zref + m + LOG2(e)) * LN2f;

  } else if (role == 1) {
    // ---------------- Viterbi (raw ln domain — bit-exact vs reference) ----------------
    float4 trR[12];
    #pragma unroll
    for (int k = 0; k < 12; ++k) {
      trR[k].x = trans[(4*k+0)*Tn + j];
      trR[k].y = trans[(4*k+1)*Tn + j];
      trR[k].z = trans[(4*k+2)*Tn + j];
      trR[k].w = trans[(4*k+3)*Tn + j];
    }
    float v = startv[j] + fb[j];
    float em_cur = fb[Tn + j];
    for (int t = 1; t < len; ++t) {
      const int tn = (t + 1 < len) ? (t + 1) : t;
      const float em_nxt = fb[(size_t)tn*Tn + j];
      float bestA = -INFINITY, bestB = -INFINITY;
      int idxA = 0, idxB = 0;
      #pragma unroll
      for (int k = 0; k < 12; ++k) {
        const float4 tr = trR[k];
        const float q0 = RL(v, 4*k+0) + tr.x;
        const float q1 = RL(v, 4*k+1) + tr.y;
        const float q2 = RL(v, 4*k+2) + tr.z;
        const float q3 = RL(v, 4*k+3) + tr.w;
        // group first-occurrence argmax (strict > keeps lowest index)
        float gv = q0; int gi = 4*k;
        bool g1 = q1 > gv; gv = g1 ? q1 : gv; gi = g1 ? 4*k+1 : gi;
        bool g2 = q2 > gv; gv = g2 ? q2 : gv; gi = g2 ? 4*k+2 : gi;
        bool g3 = q3 > gv; gv = g3 ? q3 : gv; gi = g3 ? 4*k+3 : gi;
        if ((k & 1) == 0) { bool g = gv > bestA; bestA = g ? gv : bestA; idxA = g ? gi : idxA; }
        else              { bool g = gv > bestB; bestB = g ? gv : bestB; idxB = g ? gi : idxB; }
      }
      float best; int bidx;
      if (bestB > bestA || (bestB == bestA && idxB < idxA)) { best = bestB; bidx = idxB; }
      else                                                  { best = bestA; bidx = idxA; }
      bpL[t*64 + lane] = (unsigned char)bidx;
      v = best + em_cur;
      em_cur = em_nxt;
    }
    // final first-occurrence argmax across lanes
    float fv = (lane < Tn) ? v + endv[lane] : -INFINITY;
    int fi = (lane < Tn) ? lane : 64;
    #pragma unroll
    for (int off = 32; off; off >>= 1) {
      const float ov = __shfl_xor(fv, off);
      const int   oi = __shfl_xor(fi, off);
      if (ov > fv || (ov == fv && oi < fi)) { fv = ov; fi = oi; }
    }
    __syncthreads();
    if (lane == 0) {
      int tag = fi;
      predL[len - 1] = (unsigned char)tag;
      for (int t = len - 1; t >= 1; --t) {
        tag = bpL[t*64 + tag];
        predL[t - 1] = (unsigned char)tag;
      }
    }
    __syncthreads();
    #pragma unroll
    for (int it = 0; it < Sn/64; ++it) {
      const int s = it*64 + lane;
      pred_out[(size_t)b*Sn + s] = (s < len) ? (float)predL[s] : 0.f;
    }

  } else {
    // ---------------- gold score (raw ln domain) ----------------
    float g = 0.f;
    #pragma unroll
    for (int it = 0; it < Sn/64; ++it) {
      const int sg = it*64 + lane;
      if (sg < len) {
        const int la = labels[(size_t)b*Sn + sg];
        float e = fb[(size_t)sg*Tn + la];
        if (sg > 0) e += trans[labels[(size_t)b*Sn + sg - 1]*Tn + la];
        g += e;
      }
    }
    #pragma unroll
    for (int off = 32; off; off >>= 1) g += __shfl_xor(g, off);
    if (lane == 0) {
      g += startv[labels[(size_t)b*Sn]] + endv[labels[(size_t)b*Sn + len - 1]];
      wsGold[b] = g;
    }
  }
}

__global__ void loss_reduce(const float* __restrict__ wsLogZ,
                            const float* __restrict__ wsGold,
                            float* __restrict__ out)
{
  const int lane = threadIdx.x;
  float v = wsLogZ[lane] - wsGold[lane];
  #pragma unroll
  for (int off = 32; off; off >>= 1) v += __shfl_xor(v, off);
  if (lane == 0) out[0] = v;
}

extern "C" void kernel_launch(void* const* d_in, const int* in_sizes, int n_in,
                              void* d_out, int out_size, void* d_ws, size_t ws_size,
                              hipStream_t stream) {
  const float* x      = (const float*)d_in[0];
  const int*   mask   = (const int*)  d_in[1];
  const int*   labels = (const int*)  d_in[2];
  const float* W      = (const float*)d_in[3];
  const float* bias   = (const float*)d_in[4];
  const float* trans  = (const float*)d_in[5];
  const float* startv = (const float*)d_in[6];
  const float* endv   = (const float*)d_in[7];

  float* out  = (float*)d_out;
  float* feat = out;                 // output 0: features [B][S][T]
  float* pred = out + PRED_OFF;      // output 1: pred_labels as float [B][S]
  float* loss = out + LOSS_OFF;      // output 2: scalar loss
  float* wsLogZ = (float*)d_ws;      // 64 per-batch logZ (ln units)
  float* wsGold = wsLogZ + 64;       // 64 per-batch gold scores

  gemm_feat<<<(Bn*Sn)/128, 256, 0, stream>>>(x, W, bias, feat);
  crf_kernel<<<192, 64, 0, stream>>>(feat, mask, labels, trans, startv, endv, pred, wsLogZ, wsGold);
  loss_reduce<<<1, 64, 0, stream>>>(wsLogZ, wsGold, loss);
}